// Round 9
// baseline (2606.395 us; speedup 1.0000x reference)
//
#include <hip/hip_runtime.h>

// NEURAL_PYSCF_WF: out[b] = sum_c ci[c] * det( M_b[cfg[c,i], cfg[c,j]] )
// where M_b = ao[b] (32x128) @ w[0:32,:]^T  (configs only index [0,32))
//
// R8 (resubmit; R8 run hit GPU-broker timeout): software-pipelined
// pivot-free LU. R7 showed both pipes <40% busy -> exposed ds_bpermute
// latency per k-step is the wall. Step k updates the NEXT pivot row's slot
// first, issues row k+1's broadcasts, then does the remaining 3 slots' FMA
// sweep (hides the DS round-trip under VALU). Prologue broadcasts row 0;
// total bpermute count unchanged (136/det).

#define NB 4
#define MPAD 33

__device__ __forceinline__ float grp_bcast(float v, int addr4) {
  return __int_as_float(__builtin_amdgcn_ds_bpermute(addr4, __float_as_int(v)));
}

__global__ __launch_bounds__(256, 4) void wf_fused(
    const float* __restrict__ ao,    // [8192][32][128]
    const float* __restrict__ w,     // [128][128], rows 0..31 used
    const float* __restrict__ ciw,   // [128]
    const int*  __restrict__ cfg,    // [128][16], values in [0,32)
    float* __restrict__ out)         // [8192]
{
  __shared__ float M_s[NB][32][MPAD];       // 16896 B, bank = (e+m)&31
  __shared__ uint4 cfg_b[128];              // byte-packed config rows
  __shared__ float ciw_s[128];
  __shared__ float partial[64][5];          // [group][batch]

  const int tid = threadIdx.x;
  const int b0  = blockIdx.x * NB;

  // ---------- phase 0: pack configs to bytes, stage ci ----------
  if (tid < 128) {
    ciw_s[tid] = ciw[tid];
    const int4* cr = (const int4*)(cfg + tid * 16);
    int4 c0 = cr[0], c1 = cr[1], c2 = cr[2], c3 = cr[3];
    uint4 p;
    p.x = (unsigned)c0.x | ((unsigned)c0.y << 8) | ((unsigned)c0.z << 16) | ((unsigned)c0.w << 24);
    p.y = (unsigned)c1.x | ((unsigned)c1.y << 8) | ((unsigned)c1.z << 16) | ((unsigned)c1.w << 24);
    p.z = (unsigned)c2.x | ((unsigned)c2.y << 8) | ((unsigned)c2.z << 16) | ((unsigned)c2.w << 24);
    p.w = (unsigned)c3.x | ((unsigned)c3.y << 8) | ((unsigned)c3.z << 16) | ((unsigned)c3.w << 24);
    cfg_b[tid] = p;
  }

  // ---------- phase 1: M_b[e][m] = dot(ao[b,e,:], w[m,:]) ----------
  // half = tid>>7 is wave-uniform -> w addresses stay scalar loads.
  {
    const int half = tid >> 7;
    const int bi   = (tid >> 5) & 3;
    const int e    = tid & 31;
    const float* aorow = ao + ((size_t)(b0 + bi) * 32 + e) * 128;
    const float* wbase = w + half * 16 * 128;
    float acc[16];
#pragma unroll
    for (int m = 0; m < 16; ++m) acc[m] = 0.f;
    for (int n0 = 0; n0 < 128; n0 += 4) {
      const float4 av = *(const float4*)(aorow + n0);
#pragma unroll
      for (int m = 0; m < 16; ++m) {
        const float4 wv = *(const float4*)(wbase + m * 128 + n0);
        acc[m] = fmaf(av.w, wv.w, fmaf(av.z, wv.z, fmaf(av.y, wv.y, fmaf(av.x, wv.x, acc[m]))));
      }
    }
#pragma unroll
    for (int m = 0; m < 16; ++m) M_s[bi][e][half * 16 + m] = acc[m];
  }
  __syncthreads();

  // ---------- phase 2: determinants, 4 lanes/det, 4 rows/lane, no pivot ----------
  const int l  = tid & 63;
  const int li = l & 3;                 // lane in group, owns rows 4*li..4*li+3
  const int G  = tid >> 2;              // group 0..63
  int addrO[4];
#pragma unroll
  for (int o = 0; o < 4; ++o) addrO[o] = ((l & 60) | o) << 2;

  for (int bi = 0; bi < NB; ++bi) {
    const float* Mb = &M_s[bi][0][0];
    float acc = 0.f;
#pragma unroll
    for (int tt = 0; tt < 2; ++tt) {
      const int c = (tt << 6) + G;
      const uint4 cb = cfg_b[c];

      int coff[16];
      {
        const unsigned dws0 = cb.x, dws1 = cb.y, dws2 = cb.z, dws3 = cb.w;
#pragma unroll
        for (int jj = 0; jj < 4; ++jj) {
          coff[0  + jj] = (int)((dws0 >> (8 * jj)) & 0xFFu) << 2;
          coff[4  + jj] = (int)((dws1 >> (8 * jj)) & 0xFFu) << 2;
          coff[8  + jj] = (int)((dws2 >> (8 * jj)) & 0xFFu) << 2;
          coff[12 + jj] = (int)((dws3 >> (8 * jj)) & 0xFFu) << 2;
        }
      }
      unsigned dw = (li < 2) ? (li == 0 ? cb.x : cb.y) : (li == 2 ? cb.z : cb.w);
      int roff[4];
#pragma unroll
      for (int r = 0; r < 4; ++r)
        roff[r] = (int)((dw >> (8 * r)) & 0xFFu) * (MPAD * 4);

      // gather 4x16 submatrix (bank = (row+col)&31: conflict-free in group)
      float a[4][16];
#pragma unroll
      for (int r = 0; r < 4; ++r)
#pragma unroll
        for (int j = 0; j < 16; ++j)
          a[r][j] = *(const float*)((const char*)Mb + (roff[r] + coff[j]));

      // prologue: broadcast pivot row 0 (lane 0, slot 0)
      float pr[16];
#pragma unroll
      for (int j = 0; j < 16; ++j) pr[j] = grp_bcast(a[0][j], addrO[0]);

      // pipelined no-pivot LU: step k updates next pivot row's slot first,
      // issues row k+1's broadcasts, then sweeps the remaining 3 slots.
      float det = 1.f;
#pragma unroll
      for (int k = 0; k < 16; ++k) {
        const float pk = pr[k];
        det *= pk;
        float rcp;
        asm("v_rcp_f32 %0, %1" : "=v"(rcp) : "v"(pk));
        const float f0 = a[0][k] * rcp;
        const float f1 = a[1][k] * rcp;
        const float f2 = a[2][k] * rcp;
        const float f3 = a[3][k] * rcp;
        if (k < 15) {
          const int s1   = (k + 1) & 3;          // compile-time after unroll
          const int own1 = addrO[(k + 1) >> 2];
          const float fs1 = (s1 == 0) ? f0 : (s1 == 1) ? f1 : (s1 == 2) ? f2 : f3;
          // 1) update next pivot row's slot
#pragma unroll
          for (int j = k + 1; j < 16; ++j) a[s1][j] = fmaf(-fs1, pr[j], a[s1][j]);
          // 2) issue next row's broadcasts (latency hidden under step 3)
          float nr[16];
#pragma unroll
          for (int j = k + 1; j < 16; ++j) nr[j] = grp_bcast(a[s1][j], own1);
          // 3) sweep remaining 3 slots
#pragma unroll
          for (int s = 0; s < 4; ++s) {
            if (s != s1) {
              const float fs = (s == 0) ? f0 : (s == 1) ? f1 : (s == 2) ? f2 : f3;
#pragma unroll
              for (int j = k + 1; j < 16; ++j) a[s][j] = fmaf(-fs, pr[j], a[s][j]);
            }
          }
#pragma unroll
          for (int j = k + 1; j < 16; ++j) pr[j] = nr[j];
        }
      }
      acc = fmaf(det, ciw_s[c], acc);   // identity pivot order: parity even
    }
    if (li == 0) partial[G][bi] = acc;
  }
  __syncthreads();

  if (tid < NB) {
    float s = 0.f;
    for (int g2 = 0; g2 < 64; ++g2) s += partial[g2][tid];
    out[b0 + tid] = s;
  }
}

extern "C" void kernel_launch(void* const* d_in, const int* in_sizes, int n_in,
                              void* d_out, int out_size, void* d_ws, size_t ws_size,
                              hipStream_t stream) {
  (void)in_sizes; (void)n_in; (void)out_size; (void)d_ws; (void)ws_size;
  const float* ao  = (const float*)d_in[0];
  const float* w   = (const float*)d_in[1];
  const float* ciw = (const float*)d_in[2];
  const int*   cfg = (const int*)d_in[3];
  float* out = (float*)d_out;
  hipLaunchKernelGGL(wf_fused, dim3(8192 / NB), dim3(256), 0, stream, ao, w, ciw, cfg, out);
}

// Round 11
// 437.128 us; speedup vs baseline: 5.9625x; 5.9625x over previous
//
#include <hip/hip_runtime.h>

// NEURAL_PYSCF_WF: out[b] = sum_c ci[c] * det( M_b[cfg[c,i], cfg[c,j]] )
// where M_b = ao[b] (32x128) @ w[0:32,:]^T  (configs only index [0,32))
//
// R10 (resubmit; R10 run hit GPU-broker timeout): revert to R7 pivot-free
// LU (R9's software pipeline spilled: +32 loop-carried VGPRs in a 16-deep
// unrolled loop -> scratch, 8.5 GB writes). New lever: LDS diet 20992 ->
// 19968 B (drop ciw_s, unpad partial) so the 64-VGPR kernel reaches
// 8 blocks/CU = 32 waves/CU (was LDS-capped at 7). TLP, not ILP, now
// hides the per-k ds_bpermute chain.

#define NB 4
#define MPAD 33

__device__ __forceinline__ float grp_bcast(float v, int addr4) {
  return __int_as_float(__builtin_amdgcn_ds_bpermute(addr4, __float_as_int(v)));
}

__global__ __launch_bounds__(256, 4) void wf_fused(
    const float* __restrict__ ao,    // [8192][32][128]
    const float* __restrict__ w,     // [128][128], rows 0..31 used
    const float* __restrict__ ciw,   // [128]
    const int*  __restrict__ cfg,    // [128][16], values in [0,32)
    float* __restrict__ out)         // [8192]
{
  __shared__ float M_s[NB][32][MPAD];       // 16896 B, bank = (e+m)&31
  __shared__ uint4 cfg_b[128];              // 2048 B byte-packed config rows
  __shared__ float partial[64][4];          // 1024 B [group][batch]
                                            // total 19968 B -> 8 blocks/CU

  const int tid = threadIdx.x;
  const int b0  = blockIdx.x * NB;

  // ---------- phase 0: pack configs to bytes ----------
  if (tid < 128) {
    const int4* cr = (const int4*)(cfg + tid * 16);
    int4 c0 = cr[0], c1 = cr[1], c2 = cr[2], c3 = cr[3];
    uint4 p;
    p.x = (unsigned)c0.x | ((unsigned)c0.y << 8) | ((unsigned)c0.z << 16) | ((unsigned)c0.w << 24);
    p.y = (unsigned)c1.x | ((unsigned)c1.y << 8) | ((unsigned)c1.z << 16) | ((unsigned)c1.w << 24);
    p.z = (unsigned)c2.x | ((unsigned)c2.y << 8) | ((unsigned)c2.z << 16) | ((unsigned)c2.w << 24);
    p.w = (unsigned)c3.x | ((unsigned)c3.y << 8) | ((unsigned)c3.z << 16) | ((unsigned)c3.w << 24);
    cfg_b[tid] = p;
  }

  // ---------- phase 1: M_b[e][m] = dot(ao[b,e,:], w[m,:]) ----------
  // half = tid>>7 is wave-uniform -> w addresses stay scalar loads.
  {
    const int half = tid >> 7;
    const int bi   = (tid >> 5) & 3;
    const int e    = tid & 31;
    const float* aorow = ao + ((size_t)(b0 + bi) * 32 + e) * 128;
    const float* wbase = w + half * 16 * 128;
    float acc[16];
#pragma unroll
    for (int m = 0; m < 16; ++m) acc[m] = 0.f;
    for (int n0 = 0; n0 < 128; n0 += 4) {
      const float4 av = *(const float4*)(aorow + n0);
#pragma unroll
      for (int m = 0; m < 16; ++m) {
        const float4 wv = *(const float4*)(wbase + m * 128 + n0);
        acc[m] = fmaf(av.w, wv.w, fmaf(av.z, wv.z, fmaf(av.y, wv.y, fmaf(av.x, wv.x, acc[m]))));
      }
    }
#pragma unroll
    for (int m = 0; m < 16; ++m) M_s[bi][e][half * 16 + m] = acc[m];
  }
  __syncthreads();

  // ---------- phase 2: determinants, 4 lanes/det, 4 rows/lane, no pivot ----------
  const int l  = tid & 63;
  const int li = l & 3;                 // lane in group, owns rows 4*li..4*li+3
  const int G  = tid >> 2;              // group 0..63
  int addrO[4];
#pragma unroll
  for (int o = 0; o < 4; ++o) addrO[o] = ((l & 60) | o) << 2;

  for (int bi = 0; bi < NB; ++bi) {
    const float* Mb = &M_s[bi][0][0];
    float acc = 0.f;
#pragma unroll
    for (int tt = 0; tt < 2; ++tt) {
      const int c = (tt << 6) + G;
      const float cw = ciw[c];          // L2-resident 512B table; latency hidden
      const uint4 cb = cfg_b[c];

      int coff[16];
      {
        const unsigned dws0 = cb.x, dws1 = cb.y, dws2 = cb.z, dws3 = cb.w;
#pragma unroll
        for (int jj = 0; jj < 4; ++jj) {
          coff[0  + jj] = (int)((dws0 >> (8 * jj)) & 0xFFu) << 2;
          coff[4  + jj] = (int)((dws1 >> (8 * jj)) & 0xFFu) << 2;
          coff[8  + jj] = (int)((dws2 >> (8 * jj)) & 0xFFu) << 2;
          coff[12 + jj] = (int)((dws3 >> (8 * jj)) & 0xFFu) << 2;
        }
      }
      unsigned dw = (li < 2) ? (li == 0 ? cb.x : cb.y) : (li == 2 ? cb.z : cb.w);
      int roff[4];
#pragma unroll
      for (int r = 0; r < 4; ++r)
        roff[r] = (int)((dw >> (8 * r)) & 0xFFu) * (MPAD * 4);

      // gather 4x16 submatrix (bank = (row+col)&31: conflict-free in group)
      float a[4][16];
#pragma unroll
      for (int r = 0; r < 4; ++r)
#pragma unroll
        for (int j = 0; j < 16; ++j)
          a[r][j] = *(const float*)((const char*)Mb + (roff[r] + coff[j]));

      // LU without pivoting: pivot k lives on lane k>>2, slot k&3 (static).
      float det = 1.f;
#pragma unroll
      for (int k = 0; k < 16; ++k) {
        const int slot = k & 3;          // compile-time
        const int ownA = addrO[k >> 2];  // 1 VGPR, precomputed
        float pr[16];
#pragma unroll
        for (int j = k; j < 16; ++j)
          pr[j] = grp_bcast(a[slot][j], ownA);
        const float pk = pr[k];
        det *= pk;
        float rcp;
        asm("v_rcp_f32 %0, %1" : "=v"(rcp) : "v"(pk));
        const float f0 = a[0][k] * rcp;
        const float f1 = a[1][k] * rcp;
        const float f2 = a[2][k] * rcp;
        const float f3 = a[3][k] * rcp;
#pragma unroll
        for (int j = k + 1; j < 16; ++j) {
          a[0][j] = fmaf(-f0, pr[j], a[0][j]);   // retired rows: harmless garbage
          a[1][j] = fmaf(-f1, pr[j], a[1][j]);
          a[2][j] = fmaf(-f2, pr[j], a[2][j]);
          a[3][j] = fmaf(-f3, pr[j], a[3][j]);
        }
      }
      acc = fmaf(det, cw, acc);          // identity pivot order: parity even
    }
    if (li == 0) partial[G][bi] = acc;
  }
  __syncthreads();

  if (tid < NB) {
    float s = 0.f;
    for (int g2 = 0; g2 < 64; ++g2) s += partial[g2][tid];
    out[b0 + tid] = s;
  }
}

extern "C" void kernel_launch(void* const* d_in, const int* in_sizes, int n_in,
                              void* d_out, int out_size, void* d_ws, size_t ws_size,
                              hipStream_t stream) {
  (void)in_sizes; (void)n_in; (void)out_size; (void)d_ws; (void)ws_size;
  const float* ao  = (const float*)d_in[0];
  const float* w   = (const float*)d_in[1];
  const float* ciw = (const float*)d_in[2];
  const int*   cfg = (const int*)d_in[3];
  float* out = (float*)d_out;
  hipLaunchKernelGGL(wf_fused, dim3(8192 / NB), dim3(256), 0, stream, ao, w, ciw, cfg, out);
}